// Round 3
// baseline (1412.559 us; speedup 1.0000x reference)
//
#include <hip/hip_runtime.h>
#include <hip/hip_bf16.h>

typedef __attribute__((ext_vector_type(8))) short short8;
typedef __attribute__((ext_vector_type(4))) float f32x4;
using bf16_t = __hip_bfloat16;
using bf162_t = __hip_bfloat162;

#define FD 512

__device__ __forceinline__ float ldf(const void* p, size_t i, int f32) {
  return f32 ? ((const float*)p)[i] : __bfloat162float(((const bf16_t*)p)[i]);
}

// ---------------- diagnostics ----------------
__global__ void canary_k(unsigned int* out, int nwords) {
  int i = blockIdx.x * 256 + threadIdx.x;
  if (i < nwords) out[i] = 0x42C842C8u;  // ~100.0 under both bf16 and fp32 readings
}

// flag=1 if h_disease looks like fp32, 0 if bf16 (low 16 bits of words sane as bf16?)
__global__ void detect_k(const unsigned int* w, int nwords, int* flag) {
  __shared__ int cnt_s;
  if (threadIdx.x == 0) cnt_s = 0;
  __syncthreads();
  int c = 0;
  for (int i = threadIdx.x; i < nwords; i += 256) {
    unsigned lo = w[i] & 0xFFFFu;
    unsigned ex = (lo >> 7) & 0xFFu;
    if (lo == 0u || (ex >= 100u && ex <= 140u)) c++;
  }
  atomicAdd(&cnt_s, c);
  __syncthreads();
  if (threadIdx.x == 0) *flag = (2 * cnt_s < nwords) ? 1 : 0;
}

__global__ void conv_h_k(const void* src, bf16_t* dst, int n, const int* flag) {
  int f = *flag;
  int i = blockIdx.x * 256 + threadIdx.x;
  if (i < n) dst[i] = __float2bfloat16(ldf(src, i, f));
}

// ---------------- CSR build ----------------
__global__ void count_deg_k(const int* __restrict__ a_src, const int* __restrict__ a_dst,
                            const int* __restrict__ i_src, const int* __restrict__ i_dst,
                            int* __restrict__ deg, int M, int E) {
  int e = blockIdx.x * 256 + threadIdx.x;
  if (e >= E) return;
  atomicAdd(&deg[0 * M + a_dst[e]], 1);
  atomicAdd(&deg[1 * M + a_src[e]], 1);
  atomicAdd(&deg[2 * M + i_dst[e]], 1);
  atomicAdd(&deg[3 * M + i_src[e]], 1);
}

__global__ void scan_k(const int* __restrict__ deg, int* __restrict__ offs,
                       int* __restrict__ curs, int n) {
  const int r = blockIdx.x;
  const int* d = deg + r * n;
  int* off = offs + r * (n + 1);
  int* cur = curs + r * n;
  __shared__ int part[256];
  const int t = threadIdx.x;
  const int chunk = (n + 255) / 256;
  const int s0 = t * chunk;
  const int s1 = min(n, s0 + chunk);
  int sum = 0;
  for (int i = s0; i < s1; ++i) sum += d[i];
  part[t] = sum;
  __syncthreads();
  if (t == 0) {
    int run = 0;
    for (int i = 0; i < 256; ++i) { int v = part[i]; part[i] = run; run += v; }
  }
  __syncthreads();
  int run = part[t];
  for (int i = s0; i < s1; ++i) { off[i] = run; cur[i] = run; run += d[i]; }
  if (t == 255) off[n] = run;
}

__global__ void fill_k(const int* __restrict__ a_src, const int* __restrict__ a_dst,
                       const int* __restrict__ i_src, const int* __restrict__ i_dst,
                       int* __restrict__ curs, int* __restrict__ evals, int M, int E) {
  int r = blockIdx.y;
  int e = blockIdx.x * 256 + threadIdx.x;
  if (e >= E) return;
  const int* dsts[4] = {a_dst, a_src, i_dst, i_src};
  const int* vals[4] = {a_src, a_dst, i_src, i_dst};
  int d = dsts[r][e];
  int pos = atomicAdd(&curs[r * M + d], 1);
  evals[r * E + pos] = vals[r][e];
}

// ---------------- segment mean ----------------
__global__ void seg_mean_k(const bf16_t* __restrict__ h, const int* __restrict__ off,
                           const int* __restrict__ ev, bf16_t* __restrict__ mean) {
  const int node = blockIdx.x;
  const int t = threadIdx.x;
  const int s = off[node], e = off[node + 1];
  __shared__ int nbrs[512];
  float a0 = 0.f, a1 = 0.f;
  for (int base = s; base < e; base += 512) {
    int cnt = min(512, e - base);
    for (int j = t; j < cnt; j += 256) nbrs[j] = ev[base + j];
    __syncthreads();
    for (int j = 0; j < cnt; ++j) {
      bf162_t v = *(const bf162_t*)(h + (size_t)nbrs[j] * FD + 2 * t);
      a0 += __bfloat162float(v.x);
      a1 += __bfloat162float(v.y);
    }
    __syncthreads();
  }
  int deg = e - s;
  float inv = deg > 0 ? 1.f / (float)deg : 0.f;
  bf162_t o;
  o.x = __float2bfloat16(a0 * inv);
  o.y = __float2bfloat16(a1 * inv);
  *(bf162_t*)(mean + (size_t)node * FD + 2 * t) = o;
}

// ---------------- weight prep ----------------
__global__ void transpose_sum_k(const void* s0, unsigned long long o0, const void* s1,
                                unsigned long long o1, const void* s2, unsigned long long o2,
                                bf16_t* __restrict__ dst, const int* flag) {
  int f = *flag;
  __shared__ float tile[32][33];
  const int nb = blockIdx.x * 32;
  const int kb = blockIdx.y * 32;
  const int tx = threadIdx.x, ty = threadIdx.y;
  for (int j = 0; j < 32; j += 8) {
    size_t k = kb + ty + j, n = nb + tx;
    float v = ldf(s0, o0 + k * FD + n, f);
    if (s1) v += ldf(s1, o1 + k * FD + n, f);
    if (s2) v += ldf(s2, o2 + k * FD + n, f);
    tile[ty + j][tx] = v;
  }
  __syncthreads();
  for (int j = 0; j < 32; j += 8)
    dst[(size_t)(nb + ty + j) * FD + kb + tx] = __float2bfloat16(tile[tx][ty + j]);
}

__global__ void prep_bias_k(const void* b1, const void* b2, const void* pbd, const void* pbp,
                            float* __restrict__ out, const int* flag) {
  int f = *flag;
  for (int c = threadIdx.x; c < FD; c += 256) {
    out[0 * FD + c] = ldf(b1, 1 * FD + c, f);
    out[1 * FD + c] = ldf(b1, 0 * FD + c, f) + ldf(b1, 2 * FD + c, f) + ldf(b1, 3 * FD + c, f);
    out[2 * FD + c] = ldf(b2, 1 * FD + c, f);
    out[3 * FD + c] = ldf(b2, 0 * FD + c, f) + ldf(b2, 2 * FD + c, f) + ldf(b2, 3 * FD + c, f);
    out[4 * FD + c] = ldf(pbd, c, f);
    out[5 * FD + c] = ldf(pbp, c, f);
  }
}

// ---------------- GEMM ----------------
// MODE 0: C = A@B + bias (fp32)  MODE 1: C += A@B (fp32)
// MODE 2: C = A@B + bias, stored to output half `half` with dtype chosen by *oflag
template <int MODE>
__global__ __launch_bounds__(256) void gemm_k(const short* __restrict__ A,
                                              const short* __restrict__ Bt,
                                              const float* __restrict__ bias,
                                              void* __restrict__ Cout, int M,
                                              const int* oflag, int half) {
  __shared__ __align__(16) short sA[128 * 32];
  __shared__ __align__(16) short sB[128 * 32];
  const int t = threadIdx.x;
  const int m0 = blockIdx.x * 128;
  const int n0 = blockIdx.y * 128;
  const int lane = t & 63;
  const int w = t >> 6;
  const int wm = (w & 1) * 64;
  const int wn = (w >> 1) * 64;
  const int q = lane >> 4;
  const int r16 = lane & 15;
  int of32 = 0;
  if (MODE == 2) of32 = *oflag;

  f32x4 acc[4][4];
#pragma unroll
  for (int i = 0; i < 4; ++i)
#pragma unroll
    for (int j = 0; j < 4; ++j) acc[i][j] = (f32x4){0.f, 0.f, 0.f, 0.f};

  const int row0 = t >> 2;
  const int kq0 = (t & 3) * 8;

  for (int kb = 0; kb < 16; ++kb) {
    const int k0 = kb * 32;
    uint4 va0 = make_uint4(0, 0, 0, 0), va1 = make_uint4(0, 0, 0, 0);
    const int gr0 = m0 + row0, gr1 = m0 + row0 + 64;
    if (gr0 < M) va0 = *(const uint4*)(A + (size_t)gr0 * FD + k0 + kq0);
    if (gr1 < M) va1 = *(const uint4*)(A + (size_t)gr1 * FD + k0 + kq0);
    uint4 vb0 = *(const uint4*)(Bt + (size_t)(n0 + row0) * FD + k0 + kq0);
    uint4 vb1 = *(const uint4*)(Bt + (size_t)(n0 + row0 + 64) * FD + k0 + kq0);
    __syncthreads();
    *(uint4*)(sA + row0 * 32 + kq0) = va0;
    *(uint4*)(sA + (row0 + 64) * 32 + kq0) = va1;
    *(uint4*)(sB + row0 * 32 + kq0) = vb0;
    *(uint4*)(sB + (row0 + 64) * 32 + kq0) = vb1;
    __syncthreads();
    short8 af[4], bfr[4];
#pragma unroll
    for (int i = 0; i < 4; ++i) {
      af[i] = *(const short8*)(sA + (wm + i * 16 + r16) * 32 + q * 8);
      bfr[i] = *(const short8*)(sB + (wn + i * 16 + r16) * 32 + q * 8);
    }
#pragma unroll
    for (int i = 0; i < 4; ++i)
#pragma unroll
      for (int j = 0; j < 4; ++j)
        acc[i][j] = __builtin_amdgcn_mfma_f32_16x16x32_bf16(af[i], bfr[j], acc[i][j], 0, 0, 0);
  }
  __syncthreads();

  float* outf = (float*)Cout + (size_t)half * M * FD;
  bf16_t* outb = (bf16_t*)Cout + (size_t)half * M * FD;

#pragma unroll
  for (int i = 0; i < 4; ++i) {
#pragma unroll
    for (int rg = 0; rg < 4; ++rg) {
      int gr = m0 + wm + i * 16 + q * 4 + rg;  // C/D: col=lane&15, row=(lane>>4)*4+reg
      if (gr >= M) continue;
#pragma unroll
      for (int j = 0; j < 4; ++j) {
        int col = n0 + wn + j * 16 + r16;
        size_t idx = (size_t)gr * FD + col;
        float v = acc[i][j][rg];
        if (MODE == 0)
          ((float*)Cout)[idx] = v + bias[col];
        else if (MODE == 1)
          ((float*)Cout)[idx] += v;
        else {
          float y = v + bias[col];
          if (of32)
            outf[idx] = y;
          else
            outb[idx] = __float2bfloat16(y);
        }
      }
    }
  }
}

// ---------------- BatchNorm + ReLU ----------------
__global__ void bn_stats_k(const float* __restrict__ x, int M, float* __restrict__ colsum,
                           float* __restrict__ colsq) {
  const int t = threadIdx.x;
  int rows_per = (M + gridDim.x - 1) / gridDim.x;
  int r0 = blockIdx.x * rows_per;
  int r1 = min(M, r0 + rows_per);
  float s0 = 0.f, s1 = 0.f, q0 = 0.f, q1 = 0.f;
  for (int r = r0; r < r1; ++r) {
    float a = x[(size_t)r * FD + t];
    float b = x[(size_t)r * FD + t + 256];
    s0 += a; q0 += a * a;
    s1 += b; q1 += b * b;
  }
  atomicAdd(&colsum[t], s0);
  atomicAdd(&colsum[t + 256], s1);
  atomicAdd(&colsq[t], q0);
  atomicAdd(&colsq[t + 256], q1);
}

__global__ void bn_finalize_k(const float* __restrict__ colsum, const float* __restrict__ colsq,
                              const void* gamma, const void* beta, unsigned long long goff,
                              float M, float* __restrict__ scale, float* __restrict__ shift,
                              const int* flag) {
  int f = *flag;
  for (int c = threadIdx.x; c < FD; c += 256) {
    float m = colsum[c] / M;
    float v = fmaxf(colsq[c] / M - m * m, 0.f);
    float sc = ldf(gamma, goff + c, f) * rsqrtf(v + 1e-5f);
    scale[c] = sc;
    shift[c] = ldf(beta, goff + c, f) - m * sc;
  }
}

__global__ void bn_apply_k(const float* __restrict__ x, const float* __restrict__ scale,
                           const float* __restrict__ shift, bf16_t* __restrict__ out, int total2) {
  int p = blockIdx.x * 256 + threadIdx.x;
  if (p >= total2) return;
  int e = p * 2;
  int col = e & (FD - 1);
  float2 xv = *(const float2*)(x + e);
  bf162_t o;
  o.x = __float2bfloat16(fmaxf(0.f, xv.x * scale[col] + shift[col]));
  o.y = __float2bfloat16(fmaxf(0.f, xv.y * scale[col + 1] + shift[col + 1]));
  *(bf162_t*)(out + e) = o;
}

// ---------------- host orchestration ----------------
extern "C" void kernel_launch(void* const* d_in, const int* in_sizes, int n_in,
                              void* d_out, int out_size, void* d_ws, size_t ws_size,
                              hipStream_t stream) {
  const int Mn = in_sizes[0] / FD;
  const int E = in_sizes[14];
  const size_t SZ = (size_t)FD * FD;

  const void* hd_raw = d_in[0];
  const void* hp_raw = d_in[1];
  const void* Ws1 = d_in[2];
  const void* Wn1 = d_in[3];
  const void* b1 = d_in[4];
  const void* Ws2 = d_in[5];
  const void* Wn2 = d_in[6];
  const void* b2 = d_in[7];
  const void* bng = d_in[8];
  const void* bnb = d_in[9];
  const void* pWd = d_in[10];
  const void* pbd = d_in[11];
  const void* pWp = d_in[12];
  const void* pbp = d_in[13];
  const int* a_src = (const int*)d_in[14];
  const int* a_dst = (const int*)d_in[15];
  const int* i_src = (const int*)d_in[16];
  const int* i_dst = (const int*)d_in[17];

  char* w = (char*)d_ws;
  auto alloc = [&](size_t bytes) {
    char* p = w;
    w += (bytes + 255) & ~(size_t)255;
    return p;
  };
  bf16_t* Bt = (bf16_t*)alloc(14 * SZ * 2);
  float* biasf = (float*)alloc(6 * FD * 4);
  float* stats = (float*)alloc(4 * FD * 4);
  int* dtflag = (int*)alloc(256);
  int* deg = (int*)alloc((size_t)4 * Mn * 4);
  int* offs = (int*)alloc((size_t)4 * (Mn + 1) * 4);
  int* curs = (int*)alloc((size_t)4 * Mn * 4);
  int* evals = (int*)alloc((size_t)4 * E * 4);
  float* accd = (float*)alloc((size_t)Mn * FD * 4);
  float* accp = (float*)alloc((size_t)Mn * FD * 4);
  bf16_t* h_d = (bf16_t*)alloc((size_t)Mn * FD * 2);  // canonical input, then BN output
  bf16_t* h_p = (bf16_t*)alloc((size_t)Mn * FD * 2);
  bf16_t* meanb = (bf16_t*)d_out;  // scratch, overwritten by final projections

  canary_k<<<(out_size / 2 + 255) / 256, 256, 0, stream>>>((unsigned int*)d_out, out_size / 2);
  detect_k<<<1, 256, 0, stream>>>((const unsigned int*)hd_raw, 4096, dtflag);
  int nh = Mn * FD;
  conv_h_k<<<(nh + 255) / 256, 256, 0, stream>>>(hd_raw, h_d, nh, dtflag);
  conv_h_k<<<(nh + 255) / 256, 256, 0, stream>>>(hp_raw, h_p, nh, dtflag);

  hipMemsetAsync(deg, 0, (size_t)4 * Mn * 4, stream);
  int eb = (E + 255) / 256;
  count_deg_k<<<eb, 256, 0, stream>>>(a_src, a_dst, i_src, i_dst, deg, Mn, E);
  scan_k<<<4, 256, 0, stream>>>(deg, offs, curs, Mn);
  fill_k<<<dim3(eb, 4), 256, 0, stream>>>(a_src, a_dst, i_src, i_dst, curs, evals, Mn, E);

  dim3 tg(16, 16), tb(32, 8);
  for (unsigned long long r = 0; r < 4; ++r)
    transpose_sum_k<<<tg, tb, 0, stream>>>(Wn1, r * SZ, nullptr, 0, nullptr, 0, Bt + r * SZ,
                                           dtflag);
  for (unsigned long long r = 0; r < 4; ++r)
    transpose_sum_k<<<tg, tb, 0, stream>>>(Wn2, r * SZ, nullptr, 0, nullptr, 0,
                                           Bt + (4 + r) * SZ, dtflag);
  transpose_sum_k<<<tg, tb, 0, stream>>>(Ws1, 0 * SZ, Ws1, 2 * SZ, Ws1, 3 * SZ, Bt + 8 * SZ,
                                         dtflag);
  transpose_sum_k<<<tg, tb, 0, stream>>>(Ws1, 1 * SZ, nullptr, 0, nullptr, 0, Bt + 9 * SZ,
                                         dtflag);
  transpose_sum_k<<<tg, tb, 0, stream>>>(Ws2, 0 * SZ, Ws2, 2 * SZ, Ws2, 3 * SZ, Bt + 10 * SZ,
                                         dtflag);
  transpose_sum_k<<<tg, tb, 0, stream>>>(Ws2, 1 * SZ, nullptr, 0, nullptr, 0, Bt + 11 * SZ,
                                         dtflag);
  transpose_sum_k<<<tg, tb, 0, stream>>>(pWd, 0, nullptr, 0, nullptr, 0, Bt + 12 * SZ, dtflag);
  transpose_sum_k<<<tg, tb, 0, stream>>>(pWp, 0, nullptr, 0, nullptr, 0, Bt + 13 * SZ, dtflag);
  prep_bias_k<<<1, 256, 0, stream>>>(b1, b2, pbd, pbp, biasf, dtflag);

  dim3 ggrid((Mn + 127) / 128, 4);

  auto run_bn = [&](const float* acc, unsigned long long goff, bf16_t* hout) {
    hipMemsetAsync(stats, 0, 2 * FD * 4, stream);
    bn_stats_k<<<256, 256, 0, stream>>>(acc, Mn, stats, stats + FD);
    bn_finalize_k<<<1, 256, 0, stream>>>(stats, stats + FD, bng, bnb, goff, (float)Mn,
                                         stats + 2 * FD, stats + 3 * FD, dtflag);
    bn_apply_k<<<(Mn * FD / 2 + 255) / 256, 256, 0, stream>>>(acc, stats + 2 * FD, stats + 3 * FD,
                                                              hout, Mn * FD / 2);
  };

  auto layer = [&](int wn0, int wsp, int wsd, const float* bd, const float* bp,
                   unsigned long long goff_d, unsigned long long goff_p) {
    gemm_k<0><<<ggrid, 256, 0, stream>>>((const short*)h_d, (const short*)(Bt + wsd * SZ), bd,
                                         accd, Mn, dtflag, 0);
    seg_mean_k<<<Mn, 256, 0, stream>>>(h_p, offs + 1 * (Mn + 1), evals + 1 * (size_t)E, meanb);
    gemm_k<1><<<ggrid, 256, 0, stream>>>((const short*)meanb, (const short*)(Bt + (wn0 + 1) * SZ),
                                         nullptr, accd, Mn, dtflag, 0);
    gemm_k<0><<<ggrid, 256, 0, stream>>>((const short*)h_p, (const short*)(Bt + wsp * SZ), bp,
                                         accp, Mn, dtflag, 0);
    seg_mean_k<<<Mn, 256, 0, stream>>>(h_d, offs + 0 * (Mn + 1), evals + 0 * (size_t)E, meanb);
    gemm_k<1><<<ggrid, 256, 0, stream>>>((const short*)meanb, (const short*)(Bt + (wn0 + 0) * SZ),
                                         nullptr, accp, Mn, dtflag, 0);
    seg_mean_k<<<Mn, 256, 0, stream>>>(h_p, offs + 2 * (Mn + 1), evals + 2 * (size_t)E, meanb);
    gemm_k<1><<<ggrid, 256, 0, stream>>>((const short*)meanb, (const short*)(Bt + (wn0 + 2) * SZ),
                                         nullptr, accp, Mn, dtflag, 0);
    seg_mean_k<<<Mn, 256, 0, stream>>>(h_p, offs + 3 * (Mn + 1), evals + 3 * (size_t)E, meanb);
    gemm_k<1><<<ggrid, 256, 0, stream>>>((const short*)meanb, (const short*)(Bt + (wn0 + 3) * SZ),
                                         nullptr, accp, Mn, dtflag, 0);
    run_bn(accd, goff_d, h_d);  // all reads of h_d/h_p above are complete
    run_bn(accp, goff_p, h_p);
  };

  layer(0, 8, 9, biasf + 0 * FD, biasf + 1 * FD, 0ULL * FD, 1ULL * FD);
  layer(4, 10, 11, biasf + 2 * FD, biasf + 3 * FD, 2ULL * FD, 3ULL * FD);

  gemm_k<2><<<ggrid, 256, 0, stream>>>((const short*)h_d, (const short*)(Bt + 12 * SZ),
                                       biasf + 4 * FD, d_out, Mn, dtflag, 0);
  gemm_k<2><<<ggrid, 256, 0, stream>>>((const short*)h_p, (const short*)(Bt + 13 * SZ),
                                       biasf + 5 * FD, d_out, Mn, dtflag, 1);
}

// Round 4
// 1117.942 us; speedup vs baseline: 1.2635x; 1.2635x over previous
//
#include <hip/hip_runtime.h>
#include <hip/hip_bf16.h>

typedef __attribute__((ext_vector_type(8))) short short8;
typedef __attribute__((ext_vector_type(4))) float f32x4;
using bf16_t = __hip_bfloat16;
using bf162_t = __hip_bfloat162;

#define FD 512

__device__ __forceinline__ float ldf(const void* p, size_t i, int f32) {
  return f32 ? ((const float*)p)[i] : __bfloat162float(((const bf16_t*)p)[i]);
}

// CK-pattern async global->LDS, 16B per lane (global_load_lds_dwordx4)
__device__ __forceinline__ void glds16(const bf16_t* g, short* l) {
  __builtin_amdgcn_global_load_lds(
      (const __attribute__((address_space(1))) unsigned int*)g,
      (__attribute__((address_space(3))) unsigned int*)(uintptr_t)l, 16, 0, 0);
}

// ---------------- dtype detect (fp32 vs bf16 device tensors) ----------------
__global__ void detect_k(const unsigned int* w, int nwords, int* flag) {
  __shared__ int cnt_s;
  if (threadIdx.x == 0) cnt_s = 0;
  __syncthreads();
  int c = 0;
  for (int i = threadIdx.x; i < nwords; i += 256) {
    unsigned lo = w[i] & 0xFFFFu;
    unsigned ex = (lo >> 7) & 0xFFu;
    if (lo == 0u || (ex >= 100u && ex <= 140u)) c++;
  }
  atomicAdd(&cnt_s, c);
  __syncthreads();
  if (threadIdx.x == 0) *flag = (2 * cnt_s < nwords) ? 1 : 0;
}

// convert h to canonical bf16, zero-fill pad rows (npad >= n)
__global__ void conv_h_k(const void* src, bf16_t* dst, int n, int npad, const int* flag) {
  int f = *flag;
  int e = (blockIdx.x * 256 + threadIdx.x) * 4;
  if (e >= npad) return;
  bf162_t o0, o1;
  if (e + 3 < n) {
    o0.x = __float2bfloat16(ldf(src, e + 0, f));
    o0.y = __float2bfloat16(ldf(src, e + 1, f));
    o1.x = __float2bfloat16(ldf(src, e + 2, f));
    o1.y = __float2bfloat16(ldf(src, e + 3, f));
  } else {
    float v[4];
    for (int u = 0; u < 4; ++u) v[u] = (e + u < n) ? ldf(src, e + u, f) : 0.f;
    o0.x = __float2bfloat16(v[0]); o0.y = __float2bfloat16(v[1]);
    o1.x = __float2bfloat16(v[2]); o1.y = __float2bfloat16(v[3]);
  }
  *(bf162_t*)(dst + e) = o0;
  *(bf162_t*)(dst + e + 2) = o1;
}

// ---------------- CSR build ----------------
__global__ void count_deg_k(const int* __restrict__ a_src, const int* __restrict__ a_dst,
                            const int* __restrict__ i_src, const int* __restrict__ i_dst,
                            int* __restrict__ deg, int M, int E) {
  int e = blockIdx.x * 256 + threadIdx.x;
  if (e >= E) return;
  atomicAdd(&deg[0 * M + a_dst[e]], 1);
  atomicAdd(&deg[1 * M + a_src[e]], 1);
  atomicAdd(&deg[2 * M + i_dst[e]], 1);
  atomicAdd(&deg[3 * M + i_src[e]], 1);
}

__global__ void scan_k(const int* __restrict__ deg, int* __restrict__ offs,
                       int* __restrict__ curs, int n) {
  const int r = blockIdx.x;
  const int* d = deg + r * n;
  int* off = offs + r * (n + 1);
  int* cur = curs + r * n;
  __shared__ int part[256];
  const int t = threadIdx.x;
  const int chunk = (n + 255) / 256;
  const int s0 = t * chunk;
  const int s1 = min(n, s0 + chunk);
  int sum = 0;
  for (int i = s0; i < s1; ++i) sum += d[i];
  part[t] = sum;
  __syncthreads();
  if (t == 0) {
    int run = 0;
    for (int i = 0; i < 256; ++i) { int v = part[i]; part[i] = run; run += v; }
  }
  __syncthreads();
  int run = part[t];
  for (int i = s0; i < s1; ++i) { off[i] = run; cur[i] = run; run += d[i]; }
  if (t == 255) off[n] = run;
}

__global__ void fill_k(const int* __restrict__ a_src, const int* __restrict__ a_dst,
                       const int* __restrict__ i_src, const int* __restrict__ i_dst,
                       int* __restrict__ curs, int* __restrict__ evals, int M, int E) {
  int r = blockIdx.y;
  int e = blockIdx.x * 256 + threadIdx.x;
  if (e >= E) return;
  const int* dsts[4] = {a_dst, a_src, i_dst, i_src};
  const int* vals[4] = {a_src, a_dst, i_src, i_dst};
  int d = dsts[r][e];
  int pos = atomicAdd(&curs[r * M + d], 1);
  evals[r * E + pos] = vals[r][e];
}

// ---------------- fused segment mean: all 4 relations, wave-per-neighbor ----------------
__global__ void seg_mean4_k(const bf16_t* __restrict__ hd, const bf16_t* __restrict__ hp,
                            const int* __restrict__ offs, const int* __restrict__ evals,
                            int Mn, int E, bf16_t* m0b, bf16_t* m1b, bf16_t* m2b, bf16_t* m3b) {
  const int r = blockIdx.y;
  const int node = blockIdx.x;  // grid.x = Mpad; pads write zeros
  const bf16_t* h = (r == 0) ? hd : hp;
  bf16_t* mb = (r == 0) ? m0b : (r == 1) ? m1b : (r == 2) ? m2b : m3b;
  const int* off = offs + r * (Mn + 1);
  const int* ev = evals + (size_t)r * E;
  int s = 0, e = 0;
  if (node < Mn) { s = off[node]; e = off[node + 1]; }
  const int t = threadIdx.x, lane = t & 63, v = t >> 6;
  float a[8] = {0.f, 0.f, 0.f, 0.f, 0.f, 0.f, 0.f, 0.f};
  for (int c = s + v; c < e; c += 4) {
    int nb = ev[c];
    uint4 u = *(const uint4*)(h + (size_t)nb * FD + lane * 8);
    bf162_t* pr = (bf162_t*)&u;
#pragma unroll
    for (int i = 0; i < 4; ++i) {
      a[2 * i] += __bfloat162float(pr[i].x);
      a[2 * i + 1] += __bfloat162float(pr[i].y);
    }
  }
  __shared__ float red[4][512];
#pragma unroll
  for (int u = 0; u < 8; ++u) red[v][lane * 8 + u] = a[u];
  __syncthreads();
  float inv = (e > s) ? 1.f / (float)(e - s) : 0.f;
  int c0 = 2 * t;
  float x0 = (red[0][c0] + red[1][c0] + red[2][c0] + red[3][c0]) * inv;
  float x1 = (red[0][c0 + 1] + red[1][c0 + 1] + red[2][c0 + 1] + red[3][c0 + 1]) * inv;
  bf162_t o;
  o.x = __float2bfloat16(x0);
  o.y = __float2bfloat16(x1);
  *(bf162_t*)(mb + (size_t)node * FD + c0) = o;
}

// ---------------- fused weight transpose: dst[n][k] = sum of up to 3 W[k][n] ----------------
struct TSlots {
  int s0[14], s1[14], s2[14];
  unsigned long long o0[14], o1[14], o2[14];
};

__global__ void transpose_all_k(const void* p0, const void* p1, const void* p2, const void* p3,
                                const void* p4, const void* p5, TSlots ts,
                                bf16_t* __restrict__ BtAll, const int* flag) {
  int f = *flag;
  const void* bases[6] = {p0, p1, p2, p3, p4, p5};
  const int z = blockIdx.z;
  const void* s0 = bases[ts.s0[z]];
  const void* s1 = (ts.s1[z] >= 0) ? bases[ts.s1[z]] : nullptr;
  const void* s2 = (ts.s2[z] >= 0) ? bases[ts.s2[z]] : nullptr;
  const unsigned long long o0 = ts.o0[z], o1 = ts.o1[z], o2 = ts.o2[z];
  bf16_t* dst = BtAll + (size_t)z * FD * FD;
  __shared__ float tile[32][33];
  const int nb = blockIdx.x * 32;
  const int kb = blockIdx.y * 32;
  const int tx = threadIdx.x, ty = threadIdx.y;
  for (int j = 0; j < 32; j += 8) {
    size_t k = kb + ty + j, n = nb + tx;
    float v = ldf(s0, o0 + k * FD + n, f);
    if (s1) v += ldf(s1, o1 + k * FD + n, f);
    if (s2) v += ldf(s2, o2 + k * FD + n, f);
    tile[ty + j][tx] = v;
  }
  __syncthreads();
  for (int j = 0; j < 32; j += 8)
    dst[(size_t)(nb + ty + j) * FD + kb + tx] = __float2bfloat16(tile[tx][ty + j]);
}

__global__ void prep_bias_k(const void* b1, const void* b2, const void* pbd, const void* pbp,
                            float* __restrict__ out, const int* flag) {
  int f = *flag;
  for (int c = threadIdx.x; c < FD; c += 256) {
    out[0 * FD + c] = ldf(b1, 1 * FD + c, f);
    out[1 * FD + c] = ldf(b1, 0 * FD + c, f) + ldf(b1, 2 * FD + c, f) + ldf(b1, 3 * FD + c, f);
    out[2 * FD + c] = ldf(b2, 1 * FD + c, f);
    out[3 * FD + c] = ldf(b2, 0 * FD + c, f) + ldf(b2, 2 * FD + c, f) + ldf(b2, 3 * FD + c, f);
    out[4 * FD + c] = ldf(pbd, c, f);
    out[5 * FD + c] = ldf(pbp, c, f);
  }
}

// ---------------- multi-segment fused GEMM ----------------
// C[M,512] = sum_s A_s[Mpad,512] @ B_s[512,512]^T(stored [n][k]) + bias
// EPI 0: fp32 C + fused BN column stats (sum/sumsq via atomics)
// EPI 1: output store, dtype by *oflag, offset half*M*FD elements
// 128x128 tile, 4 waves 64x64, mfma 16x16x32 bf16, BK=32, global_load_lds staging.
template <int NSEG, int EPI>
__global__ __launch_bounds__(256) void gemm_f(
    const bf16_t* __restrict__ A0, const bf16_t* __restrict__ A1,
    const bf16_t* __restrict__ A2, const bf16_t* __restrict__ A3,
    const bf16_t* __restrict__ B0, const bf16_t* __restrict__ B1,
    const bf16_t* __restrict__ B2, const bf16_t* __restrict__ B3,
    const float* __restrict__ bias, void* __restrict__ Cout, float* __restrict__ stats,
    int M, const int* oflag, int half) {
  __shared__ __align__(16) short sA[128 * 32];
  __shared__ __align__(16) short sB[128 * 32];
  const int t = threadIdx.x;
  const int n0 = blockIdx.x * 128;  // x = col-block so consecutive blocks share A (L2)
  const int m0 = blockIdx.y * 128;
  const int lane = t & 63, w = t >> 6;
  const int wm = (w & 1) * 64, wn = (w >> 1) * 64;
  const int q = lane >> 4, r16 = lane & 15;
  int of32 = 0;
  if (EPI == 1) of32 = *oflag;

  // staging: wave w fills rows [w*32, w*32+32); two glds per buffer (16 rows each)
  const int srow = w * 32 + (lane >> 2);     // + 0 / +16
  const int schunk = (lane & 3) * 8;         // shorts within 32-short row
  short* lA0 = sA + (w * 32) * 32;
  short* lA1 = sA + (w * 32 + 16) * 32;
  short* lB0 = sB + (w * 32) * 32;
  short* lB1 = sB + (w * 32 + 16) * 32;

  const bf16_t* As[4] = {A0, A1, A2, A3};
  const bf16_t* Bs[4] = {B0, B1, B2, B3};

  f32x4 acc[4][4];
#pragma unroll
  for (int i = 0; i < 4; ++i)
#pragma unroll
    for (int j = 0; j < 4; ++j) acc[i][j] = (f32x4){0.f, 0.f, 0.f, 0.f};

#pragma unroll
  for (int seg = 0; seg < NSEG; ++seg) {
    const bf16_t* pa0 = As[seg] + (size_t)(m0 + srow) * FD + schunk;
    const bf16_t* pa1 = pa0 + (size_t)16 * FD;
    const bf16_t* pb0 = Bs[seg] + (size_t)(n0 + srow) * FD + schunk;
    const bf16_t* pb1 = pb0 + (size_t)16 * FD;
    for (int kb = 0; kb < 16; ++kb) {
      __syncthreads();  // prior ds_reads done before overwriting LDS
      glds16(pa0, lA0);
      glds16(pa1, lA1);
      glds16(pb0, lB0);
      glds16(pb1, lB1);
      pa0 += 32; pa1 += 32; pb0 += 32; pb1 += 32;
      __syncthreads();  // vmcnt drained -> LDS visible
      short8 af[4], bfr[4];
#pragma unroll
      for (int i = 0; i < 4; ++i) {
        af[i] = *(const short8*)(sA + (wm + i * 16 + r16) * 32 + q * 8);
        bfr[i] = *(const short8*)(sB + (wn + i * 16 + r16) * 32 + q * 8);
      }
#pragma unroll
      for (int i = 0; i < 4; ++i)
#pragma unroll
        for (int j = 0; j < 4; ++j)
          acc[i][j] = __builtin_amdgcn_mfma_f32_16x16x32_bf16(af[i], bfr[j], acc[i][j], 0, 0, 0);
    }
  }

  float bcol[4];
#pragma unroll
  for (int j = 0; j < 4; ++j) bcol[j] = bias[n0 + wn + j * 16 + r16];

  if (EPI == 0) {
    float* Cf = (float*)Cout;
    float ps[4] = {0.f, 0.f, 0.f, 0.f}, pq[4] = {0.f, 0.f, 0.f, 0.f};
#pragma unroll
    for (int i = 0; i < 4; ++i) {
#pragma unroll
      for (int rg = 0; rg < 4; ++rg) {
        int gr = m0 + wm + i * 16 + q * 4 + rg;  // C/D: col=lane&15, row=(lane>>4)*4+reg
        if (gr >= M) continue;
#pragma unroll
        for (int j = 0; j < 4; ++j) {
          int col = n0 + wn + j * 16 + r16;
          float v = acc[i][j][rg] + bcol[j];
          Cf[(size_t)gr * FD + col] = v;
          ps[j] += v;
          pq[j] += v * v;
        }
      }
    }
#pragma unroll
    for (int j = 0; j < 4; ++j) {
      float s = ps[j], qq = pq[j];
      s += __shfl_xor(s, 16);
      s += __shfl_xor(s, 32);
      qq += __shfl_xor(qq, 16);
      qq += __shfl_xor(qq, 32);
      if (q == 0) {
        int col = n0 + wn + j * 16 + r16;
        atomicAdd(&stats[col], s);
        atomicAdd(&stats[FD + col], qq);
      }
    }
  } else {
    float* outf = (float*)Cout + (size_t)half * M * FD;
    bf16_t* outb = (bf16_t*)Cout + (size_t)half * M * FD;
#pragma unroll
    for (int i = 0; i < 4; ++i) {
#pragma unroll
      for (int rg = 0; rg < 4; ++rg) {
        int gr = m0 + wm + i * 16 + q * 4 + rg;
        if (gr >= M) continue;
#pragma unroll
        for (int j = 0; j < 4; ++j) {
          int col = n0 + wn + j * 16 + r16;
          float y = acc[i][j][rg] + bcol[j];
          if (of32)
            outf[(size_t)gr * FD + col] = y;
          else
            outb[(size_t)gr * FD + col] = __float2bfloat16(y);
        }
      }
    }
  }
}

// ---------------- BN finalize + apply ----------------
__global__ void bn_fin_k(const float* __restrict__ stats, const void* gamma, const void* beta,
                         unsigned long long goff, float M, float* __restrict__ scsh,
                         const int* flag) {
  int f = *flag;
  for (int c = threadIdx.x; c < FD; c += 256) {
    float m = stats[c] / M;
    float v = fmaxf(stats[FD + c] / M - m * m, 0.f);
    float sc = ldf(gamma, goff + c, f) * rsqrtf(v + 1e-5f);
    scsh[c] = sc;
    scsh[FD + c] = ldf(beta, goff + c, f) - m * sc;
  }
}

__global__ void bn_apply_k(const float* __restrict__ x, const float* __restrict__ scsh,
                           bf16_t* __restrict__ out, int total4) {
  int p = blockIdx.x * 256 + threadIdx.x;
  if (p >= total4) return;
  int e = p * 4;
  int col = e & (FD - 1);
  float4 xv = *(const float4*)(x + e);
  bf162_t o0, o1;
  o0.x = __float2bfloat16(fmaxf(0.f, xv.x * scsh[col] + scsh[FD + col]));
  o0.y = __float2bfloat16(fmaxf(0.f, xv.y * scsh[col + 1] + scsh[FD + col + 1]));
  o1.x = __float2bfloat16(fmaxf(0.f, xv.z * scsh[col + 2] + scsh[FD + col + 2]));
  o1.y = __float2bfloat16(fmaxf(0.f, xv.w * scsh[col + 3] + scsh[FD + col + 3]));
  *(bf162_t*)(out + e) = o0;
  *(bf162_t*)(out + e + 2) = o1;
}

// ---------------- host orchestration ----------------
extern "C" void kernel_launch(void* const* d_in, const int* in_sizes, int n_in,
                              void* d_out, int out_size, void* d_ws, size_t ws_size,
                              hipStream_t stream) {
  const int Mn = in_sizes[0] / FD;          // 20000
  const int Mp = (Mn + 127) & ~127;         // 20096 (padded rows)
  const int E = in_sizes[14];               // 320000
  const size_t SZ = (size_t)FD * FD;

  const void* hd_raw = d_in[0];
  const void* hp_raw = d_in[1];
  const void* Ws1 = d_in[2];
  const void* Wn1 = d_in[3];
  const void* b1 = d_in[4];
  const void* Ws2 = d_in[5];
  const void* Wn2 = d_in[6];
  const void* b2 = d_in[7];
  const void* bng = d_in[8];
  const void* bnb = d_in[9];
  const void* pWd = d_in[10];
  const void* pbd = d_in[11];
  const void* pWp = d_in[12];
  const void* pbp = d_in[13];
  const int* a_src = (const int*)d_in[14];
  const int* a_dst = (const int*)d_in[15];
  const int* i_src = (const int*)d_in[16];
  const int* i_dst = (const int*)d_in[17];

  char* wptr = (char*)d_ws;
  auto alloc = [&](size_t bytes) {
    char* p = wptr;
    wptr += (bytes + 255) & ~(size_t)255;
    return p;
  };
  bf16_t* Bt = (bf16_t*)alloc(14 * SZ * 2);                  // 7.3 MB
  float* biasf = (float*)alloc(6 * FD * 4);
  float* stats = (float*)alloc(4 * FD * 4);                  // [sum_d|sq_d|sum_p|sq_p]
  float* scshd = (float*)alloc(2 * FD * 4);
  float* scshp = (float*)alloc(2 * FD * 4);
  int* dtflag = (int*)alloc(256);
  int* deg = (int*)alloc((size_t)4 * Mn * 4);
  int* offs = (int*)alloc((size_t)4 * (Mn + 1) * 4);
  int* curs = (int*)alloc((size_t)4 * Mn * 4);
  int* evals = (int*)alloc((size_t)4 * E * 4);               // 5.1 MB
  float* acc = (float*)alloc((size_t)Mp * FD * 4);           // 41.2 MB (shared d/p)
  bf16_t* h_d = (bf16_t*)alloc((size_t)Mp * FD * 2);         // 20.6 MB
  bf16_t* h_p = (bf16_t*)alloc((size_t)Mp * FD * 2);
  bf16_t* mean0 = (bf16_t*)alloc((size_t)Mp * FD * 2);       // 4 x 20.6 MB
  bf16_t* mean1 = (bf16_t*)alloc((size_t)Mp * FD * 2);
  bf16_t* mean2 = (bf16_t*)alloc((size_t)Mp * FD * 2);
  bf16_t* mean3 = (bf16_t*)alloc((size_t)Mp * FD * 2);

  detect_k<<<1, 256, 0, stream>>>((const unsigned int*)hd_raw, 4096, dtflag);
  const int nh = Mn * FD, nhp = Mp * FD;
  conv_h_k<<<(nhp / 4 + 255) / 256, 256, 0, stream>>>(hd_raw, h_d, nh, nhp, dtflag);
  conv_h_k<<<(nhp / 4 + 255) / 256, 256, 0, stream>>>(hp_raw, h_p, nh, nhp, dtflag);

  hipMemsetAsync(deg, 0, (size_t)4 * Mn * 4, stream);
  int eb = (E + 255) / 256;
  count_deg_k<<<eb, 256, 0, stream>>>(a_src, a_dst, i_src, i_dst, deg, Mn, E);
  scan_k<<<4, 256, 0, stream>>>(deg, offs, curs, Mn);
  fill_k<<<dim3(eb, 4), 256, 0, stream>>>(a_src, a_dst, i_src, i_dst, curs, evals, Mn, E);

  // Bt slots: [0..3]=Wn1T[r], [4..7]=Wn2T[r], [8]=Ws1(0+2+3)T, [9]=Ws1(1)T,
  //           [10]=Ws2(0+2+3)T, [11]=Ws2(1)T, [12]=projWdT, [13]=projWpT
  TSlots ts;
  for (int z = 0; z < 14; ++z) { ts.s1[z] = -1; ts.s2[z] = -1; ts.o1[z] = 0; ts.o2[z] = 0; }
  for (int r = 0; r < 4; ++r) { ts.s0[r] = 1; ts.o0[r] = (unsigned long long)r * SZ; }
  for (int r = 0; r < 4; ++r) { ts.s0[4 + r] = 3; ts.o0[4 + r] = (unsigned long long)r * SZ; }
  ts.s0[8] = 0; ts.o0[8] = 0; ts.s1[8] = 0; ts.o1[8] = 2 * SZ; ts.s2[8] = 0; ts.o2[8] = 3 * SZ;
  ts.s0[9] = 0; ts.o0[9] = 1 * SZ;
  ts.s0[10] = 2; ts.o0[10] = 0; ts.s1[10] = 2; ts.o1[10] = 2 * SZ; ts.s2[10] = 2; ts.o2[10] = 3 * SZ;
  ts.s0[11] = 2; ts.o0[11] = 1 * SZ;
  ts.s0[12] = 4; ts.o0[12] = 0;
  ts.s0[13] = 5; ts.o0[13] = 0;
  transpose_all_k<<<dim3(16, 16, 14), dim3(32, 8), 0, stream>>>(Ws1, Wn1, Ws2, Wn2, pWd, pWp,
                                                                ts, Bt, dtflag);
  prep_bias_k<<<1, 256, 0, stream>>>(b1, b2, pbd, pbp, biasf, dtflag);

  dim3 ggrid(4, Mp / 128);  // x=col-block (A reuse across consecutive blocks)
  const int bn4 = (Mn * FD / 4 + 255) / 256;

  auto layer = [&](int wn0, int wsp, int wsd, const float* bd, const float* bp,
                   unsigned long long goff_d, unsigned long long goff_p) {
    seg_mean4_k<<<dim3(Mp, 4), 256, 0, stream>>>(h_d, h_p, offs, evals, Mn, E, mean0, mean1,
                                                 mean2, mean3);
    hipMemsetAsync(stats, 0, 4 * FD * 4, stream);
    // disease = hd@Ws[1] + mean1@Wn[1] + b  (K-concat 2 segments)
    gemm_f<2, 0><<<ggrid, 256, 0, stream>>>(h_d, mean1, nullptr, nullptr,
                                            Bt + (size_t)wsd * SZ, Bt + (size_t)(wn0 + 1) * SZ,
                                            nullptr, nullptr, bd, acc, stats, Mn, dtflag, 0);
    bn_fin_k<<<1, 256, 0, stream>>>(stats, bng, bnb, goff_d, (float)Mn, scshd, dtflag);
    bn_apply_k<<<bn4, 256, 0, stream>>>(acc, scshd, h_d, Mn * FD / 4);
    // protein = hp@(Ws0+Ws2+Ws3) + mean0@Wn0 + mean2@Wn2 + mean3@Wn3 + b  (4 segments)
    gemm_f<4, 0><<<ggrid, 256, 0, stream>>>(h_p, mean0, mean2, mean3,
                                            Bt + (size_t)wsp * SZ, Bt + (size_t)(wn0 + 0) * SZ,
                                            Bt + (size_t)(wn0 + 2) * SZ,
                                            Bt + (size_t)(wn0 + 3) * SZ, bp, acc,
                                            stats + 2 * FD, Mn, dtflag, 0);
    bn_fin_k<<<1, 256, 0, stream>>>(stats + 2 * FD, bng, bnb, goff_p, (float)Mn, scshp, dtflag);
    bn_apply_k<<<bn4, 256, 0, stream>>>(acc, scshp, h_p, Mn * FD / 4);
  };

  // bn params layout [layer][ntype][512], ntype 0=disease 1=protein
  layer(0, 8, 9, biasf + 0 * FD, biasf + 1 * FD, 0ULL * FD, 1ULL * FD);
  layer(4, 10, 11, biasf + 2 * FD, biasf + 3 * FD, 2ULL * FD, 3ULL * FD);

  // final projections -> d_out (out_d then out_p), dtype per flag
  gemm_f<1, 1><<<ggrid, 256, 0, stream>>>(h_d, nullptr, nullptr, nullptr, Bt + 12 * SZ, nullptr,
                                          nullptr, nullptr, biasf + 4 * FD, d_out, nullptr, Mn,
                                          dtflag, 0);
  gemm_f<1, 1><<<ggrid, 256, 0, stream>>>(h_p, nullptr, nullptr, nullptr, Bt + 13 * SZ, nullptr,
                                          nullptr, nullptr, biasf + 5 * FD, d_out, nullptr, Mn,
                                          dtflag, 1);
}

// Round 5
// 1070.409 us; speedup vs baseline: 1.3196x; 1.0444x over previous
//
#include <hip/hip_runtime.h>
#include <hip/hip_bf16.h>

typedef __attribute__((ext_vector_type(8))) short short8;
typedef __attribute__((ext_vector_type(4))) float f32x4;
using bf16_t = __hip_bfloat16;
using bf162_t = __hip_bfloat162;

#define FD 512

__device__ __forceinline__ float ldf(const void* p, size_t i, int f32) {
  return f32 ? ((const float*)p)[i] : __bfloat162float(((const bf16_t*)p)[i]);
}

// CK-pattern async global->LDS, 16B per lane (global_load_lds_dwordx4)
__device__ __forceinline__ void glds16(const bf16_t* g, short* l) {
  __builtin_amdgcn_global_load_lds(
      (const __attribute__((address_space(1))) unsigned int*)g,
      (__attribute__((address_space(3))) unsigned int*)(uintptr_t)l, 16, 0, 0);
}

// ---------------- dtype detect (fp32 vs bf16 device tensors) ----------------
__global__ void detect_k(const unsigned int* w, int nwords, int* flag) {
  __shared__ int cnt_s;
  if (threadIdx.x == 0) cnt_s = 0;
  __syncthreads();
  int c = 0;
  for (int i = threadIdx.x; i < nwords; i += 256) {
    unsigned lo = w[i] & 0xFFFFu;
    unsigned ex = (lo >> 7) & 0xFFu;
    if (lo == 0u || (ex >= 100u && ex <= 140u)) c++;
  }
  atomicAdd(&cnt_s, c);
  __syncthreads();
  if (threadIdx.x == 0) *flag = (2 * cnt_s < nwords) ? 1 : 0;
}

// convert h (z=0: disease, z=1: protein) to canonical bf16, zero pad rows
__global__ void conv_h_k(const void* s0, const void* s1, bf16_t* d0, bf16_t* d1, int n, int npad,
                         const int* flag) {
  int f = *flag;
  const void* src = blockIdx.y ? s1 : s0;
  bf16_t* dst = blockIdx.y ? d1 : d0;
  int e = (blockIdx.x * 256 + threadIdx.x) * 4;
  if (e >= npad) return;
  bf162_t o0, o1;
  if (e + 3 < n) {
    o0.x = __float2bfloat16(ldf(src, e + 0, f));
    o0.y = __float2bfloat16(ldf(src, e + 1, f));
    o1.x = __float2bfloat16(ldf(src, e + 2, f));
    o1.y = __float2bfloat16(ldf(src, e + 3, f));
  } else {
    float v[4];
    for (int u = 0; u < 4; ++u) v[u] = (e + u < n) ? ldf(src, e + u, f) : 0.f;
    o0.x = __float2bfloat16(v[0]); o0.y = __float2bfloat16(v[1]);
    o1.x = __float2bfloat16(v[2]); o1.y = __float2bfloat16(v[3]);
  }
  *(bf162_t*)(dst + e) = o0;
  *(bf162_t*)(dst + e + 2) = o1;
}

// ---------------- CSR build ----------------
__global__ void count_deg_k(const int* __restrict__ a_src, const int* __restrict__ a_dst,
                            const int* __restrict__ i_src, const int* __restrict__ i_dst,
                            int* __restrict__ deg, int M, int E) {
  int e = blockIdx.x * 256 + threadIdx.x;
  if (e >= E) return;
  atomicAdd(&deg[0 * M + a_dst[e]], 1);
  atomicAdd(&deg[1 * M + a_src[e]], 1);
  atomicAdd(&deg[2 * M + i_dst[e]], 1);
  atomicAdd(&deg[3 * M + i_src[e]], 1);
}

__global__ void scan_k(const int* __restrict__ deg, int* __restrict__ offs,
                       int* __restrict__ curs, int n) {
  const int r = blockIdx.x;
  const int* d = deg + r * n;
  int* off = offs + r * (n + 1);
  int* cur = curs + r * n;
  __shared__ int part[256];
  const int t = threadIdx.x;
  const int chunk = (n + 255) / 256;
  const int s0 = t * chunk;
  const int s1 = min(n, s0 + chunk);
  int sum = 0;
  for (int i = s0; i < s1; ++i) sum += d[i];
  part[t] = sum;
  __syncthreads();
  if (t == 0) {
    int run = 0;
    for (int i = 0; i < 256; ++i) { int v = part[i]; part[i] = run; run += v; }
  }
  __syncthreads();
  int run = part[t];
  for (int i = s0; i < s1; ++i) { off[i] = run; cur[i] = run; run += d[i]; }
  if (t == 255) off[n] = run;
}

__global__ void fill_k(const int* __restrict__ a_src, const int* __restrict__ a_dst,
                       const int* __restrict__ i_src, const int* __restrict__ i_dst,
                       int* __restrict__ curs, int* __restrict__ evals, int M, int E) {
  int r = blockIdx.y;
  int e = blockIdx.x * 256 + threadIdx.x;
  if (e >= E) return;
  const int* dsts[4] = {a_dst, a_src, i_dst, i_src};
  const int* vals[4] = {a_src, a_dst, i_src, i_dst};
  int d = dsts[r][e];
  int pos = atomicAdd(&curs[r * M + d], 1);
  evals[r * E + pos] = vals[r][e];
}

// ---------------- fused segment mean: all 4 relations, 4-deep MLP unroll ----------------
__global__ void seg_mean4_k(const bf16_t* __restrict__ hd, const bf16_t* __restrict__ hp,
                            const int* __restrict__ offs, const int* __restrict__ evals,
                            int Mn, int E, bf16_t* m0b, bf16_t* m1b, bf16_t* m2b, bf16_t* m3b) {
  const int r = blockIdx.y;
  const int node = blockIdx.x;  // grid.x = Mpad; pad nodes write zeros
  const bf16_t* h = (r == 0) ? hd : hp;
  bf16_t* mb = (r == 0) ? m0b : (r == 1) ? m1b : (r == 2) ? m2b : m3b;
  const int* off = offs + r * (Mn + 1);
  const int* ev = evals + (size_t)r * E;
  int s = 0, e = 0;
  if (node < Mn) { s = off[node]; e = off[node + 1]; }
  const int t = threadIdx.x, lane = t & 63, v = t >> 6;
  float a[8] = {0.f, 0.f, 0.f, 0.f, 0.f, 0.f, 0.f, 0.f};
  int c = s + v;
  // wave v owns neighbors c = s+v, s+v+4, ... ; 4 independent row loads in flight
  for (; c + 12 < e; c += 16) {
    int n0 = ev[c], n1 = ev[c + 4], n2 = ev[c + 8], n3 = ev[c + 12];
    uint4 u0 = *(const uint4*)(h + (size_t)n0 * FD + lane * 8);
    uint4 u1 = *(const uint4*)(h + (size_t)n1 * FD + lane * 8);
    uint4 u2 = *(const uint4*)(h + (size_t)n2 * FD + lane * 8);
    uint4 u3 = *(const uint4*)(h + (size_t)n3 * FD + lane * 8);
    bf162_t* p0 = (bf162_t*)&u0;
    bf162_t* p1 = (bf162_t*)&u1;
    bf162_t* p2 = (bf162_t*)&u2;
    bf162_t* p3 = (bf162_t*)&u3;
#pragma unroll
    for (int i = 0; i < 4; ++i) {
      a[2 * i] += __bfloat162float(p0[i].x) + __bfloat162float(p1[i].x) +
                  __bfloat162float(p2[i].x) + __bfloat162float(p3[i].x);
      a[2 * i + 1] += __bfloat162float(p0[i].y) + __bfloat162float(p1[i].y) +
                      __bfloat162float(p2[i].y) + __bfloat162float(p3[i].y);
    }
  }
  for (; c < e; c += 4) {
    int nb = ev[c];
    uint4 u = *(const uint4*)(h + (size_t)nb * FD + lane * 8);
    bf162_t* pr = (bf162_t*)&u;
#pragma unroll
    for (int i = 0; i < 4; ++i) {
      a[2 * i] += __bfloat162float(pr[i].x);
      a[2 * i + 1] += __bfloat162float(pr[i].y);
    }
  }
  // permuted reduce layout: col j = lane*8+u stored at [u*64+lane] -> conflict-free writes
  __shared__ float red[4][512];
#pragma unroll
  for (int u = 0; u < 8; ++u) red[v][u * 64 + lane] = a[u];
  __syncthreads();
  float inv = (e > s) ? 1.f / (float)(e - s) : 0.f;
  int j0 = 2 * t, j1 = 2 * t + 1;
  int i0 = (j0 & 7) * 64 + (j0 >> 3);
  int i1 = (j1 & 7) * 64 + (j1 >> 3);
  float x0 = (red[0][i0] + red[1][i0] + red[2][i0] + red[3][i0]) * inv;
  float x1 = (red[0][i1] + red[1][i1] + red[2][i1] + red[3][i1]) * inv;
  bf162_t o;
  o.x = __float2bfloat16(x0);
  o.y = __float2bfloat16(x1);
  *(bf162_t*)(mb + (size_t)node * FD + j0) = o;
}

// ---------------- fused weight transpose: dst[n][k] = sum of up to 3 W[k][n] ----------------
struct TSlots {
  int s0[14], s1[14], s2[14];
  unsigned long long o0[14], o1[14], o2[14];
};

__global__ void transpose_all_k(const void* p0, const void* p1, const void* p2, const void* p3,
                                const void* p4, const void* p5, TSlots ts,
                                bf16_t* __restrict__ BtAll, const int* flag) {
  int f = *flag;
  const void* bases[6] = {p0, p1, p2, p3, p4, p5};
  const int z = blockIdx.z;
  const void* s0 = bases[ts.s0[z]];
  const void* s1 = (ts.s1[z] >= 0) ? bases[ts.s1[z]] : nullptr;
  const void* s2 = (ts.s2[z] >= 0) ? bases[ts.s2[z]] : nullptr;
  const unsigned long long o0 = ts.o0[z], o1 = ts.o1[z], o2 = ts.o2[z];
  bf16_t* dst = BtAll + (size_t)z * FD * FD;
  __shared__ float tile[32][33];
  const int nb = blockIdx.x * 32;
  const int kb = blockIdx.y * 32;
  const int tx = threadIdx.x, ty = threadIdx.y;
  for (int j = 0; j < 32; j += 8) {
    size_t k = kb + ty + j, n = nb + tx;
    float v = ldf(s0, o0 + k * FD + n, f);
    if (s1) v += ldf(s1, o1 + k * FD + n, f);
    if (s2) v += ldf(s2, o2 + k * FD + n, f);
    tile[ty + j][tx] = v;
  }
  __syncthreads();
  for (int j = 0; j < 32; j += 8)
    dst[(size_t)(nb + ty + j) * FD + kb + tx] = __float2bfloat16(tile[tx][ty + j]);
}

__global__ void prep_bias_k(const void* b1, const void* b2, const void* pbd, const void* pbp,
                            float* __restrict__ out, const int* flag) {
  int f = *flag;
  for (int c = threadIdx.x; c < FD; c += 256) {
    out[0 * FD + c] = ldf(b1, 1 * FD + c, f);
    out[1 * FD + c] = ldf(b1, 0 * FD + c, f) + ldf(b1, 2 * FD + c, f) + ldf(b1, 3 * FD + c, f);
    out[2 * FD + c] = ldf(b2, 1 * FD + c, f);
    out[3 * FD + c] = ldf(b2, 0 * FD + c, f) + ldf(b2, 2 * FD + c, f) + ldf(b2, 3 * FD + c, f);
    out[4 * FD + c] = ldf(pbd, c, f);
    out[5 * FD + c] = ldf(pbp, c, f);
  }
}

// ---------------- multi-segment fused GEMM ----------------
// C[M,512] = sum_s A_s[Mpad,512] @ B_s[512,512]^T(stored [n][k]) + bias
// EPI 0: bf16 C + fused BN column stats (sum/sumsq of rounded values, atomics)
// EPI 1: output store (dtype by *oflag); blockIdx.z selects {A0,B0,half=0}/{A1,B1,half=1}
template <int NSEG, int EPI>
__global__ __launch_bounds__(256) void gemm_f(
    const bf16_t* __restrict__ A0, const bf16_t* __restrict__ A1,
    const bf16_t* __restrict__ A2, const bf16_t* __restrict__ A3,
    const bf16_t* __restrict__ B0, const bf16_t* __restrict__ B1,
    const bf16_t* __restrict__ B2, const bf16_t* __restrict__ B3,
    const float* __restrict__ bias, void* __restrict__ Cout, float* __restrict__ stats,
    int M, const int* oflag) {
  __shared__ __align__(16) short sA[128 * 32];
  __shared__ __align__(16) short sB[128 * 32];
  const int t = threadIdx.x;
  const int n0 = blockIdx.x * 128;  // x = col-block: consecutive blocks share A via L2
  const int m0 = blockIdx.y * 128;
  const int lane = t & 63, w = t >> 6;
  const int wm = (w & 1) * 64, wn = (w >> 1) * 64;
  const int q = lane >> 4, r16 = lane & 15;

  const bf16_t* As[4] = {A0, A1, A2, A3};
  const bf16_t* Bs[4] = {B0, B1, B2, B3};
  const float* biasp = bias;
  int half = 0;
  int of32 = 0;
  if (EPI == 1) {
    of32 = *oflag;
    half = blockIdx.z;
    if (half) { As[0] = A1; Bs[0] = B1; }
    biasp = bias + half * FD;
  }

  f32x4 acc[4][4];
#pragma unroll
  for (int i = 0; i < 4; ++i)
#pragma unroll
    for (int j = 0; j < 4; ++j) acc[i][j] = (f32x4){0.f, 0.f, 0.f, 0.f};

  // staging: wave w fills rows [w*32, w*32+32); two glds per buffer (16 rows each)
  const int srow = w * 32 + (lane >> 2);
  const int schunk = (lane & 3) * 8;
  short* lA0 = sA + (w * 32) * 32;
  short* lA1 = sA + (w * 32 + 16) * 32;
  short* lB0 = sB + (w * 32) * 32;
  short* lB1 = sB + (w * 32 + 16) * 32;

#pragma unroll
  for (int seg = 0; seg < NSEG; ++seg) {
    const bf16_t* pa0 = As[seg] + (size_t)(m0 + srow) * FD + schunk;
    const bf16_t* pa1 = pa0 + (size_t)16 * FD;
    const bf16_t* pb0 = Bs[seg] + (size_t)(n0 + srow) * FD + schunk;
    const bf16_t* pb1 = pb0 + (size_t)16 * FD;
    for (int kb = 0; kb < 16; ++kb) {
      __syncthreads();
      glds16(pa0, lA0);
      glds16(pa1, lA1);
      glds16(pb0, lB0);
      glds16(pb1, lB1);
      pa0 += 32; pa1 += 32; pb0 += 32; pb1 += 32;
      __syncthreads();
      short8 af[4], bfr[4];
#pragma unroll
      for (int i = 0; i < 4; ++i) {
        af[i] = *(const short8*)(sA + (wm + i * 16 + r16) * 32 + q * 8);
        bfr[i] = *(const short8*)(sB + (wn + i * 16 + r16) * 32 + q * 8);
      }
#pragma unroll
      for (int i = 0; i < 4; ++i)
#pragma unroll
        for (int j = 0; j < 4; ++j)
          acc[i][j] = __builtin_amdgcn_mfma_f32_16x16x32_bf16(af[i], bfr[j], acc[i][j], 0, 0, 0);
    }
  }

  float bcol[4];
#pragma unroll
  for (int j = 0; j < 4; ++j) bcol[j] = biasp[n0 + wn + j * 16 + r16];

  if (EPI == 0) {
    bf16_t* Cb = (bf16_t*)Cout;
    float ps[4] = {0.f, 0.f, 0.f, 0.f}, pq[4] = {0.f, 0.f, 0.f, 0.f};
#pragma unroll
    for (int i = 0; i < 4; ++i) {
#pragma unroll
      for (int rg = 0; rg < 4; ++rg) {
        int gr = m0 + wm + i * 16 + q * 4 + rg;  // C/D: col=lane&15, row=(lane>>4)*4+reg
        if (gr >= M) continue;
#pragma unroll
        for (int j = 0; j < 4; ++j) {
          int col = n0 + wn + j * 16 + r16;
          bf16_t rb = __float2bfloat16(acc[i][j][rg] + bcol[j]);
          Cb[(size_t)gr * FD + col] = rb;
          float xr = __bfloat162float(rb);  // stats of the stored (rounded) tensor
          ps[j] += xr;
          pq[j] += xr * xr;
        }
      }
    }
#pragma unroll
    for (int j = 0; j < 4; ++j) {
      float s = ps[j], qq = pq[j];
      s += __shfl_xor(s, 16);
      s += __shfl_xor(s, 32);
      qq += __shfl_xor(qq, 16);
      qq += __shfl_xor(qq, 32);
      if (q == 0) {
        int col = n0 + wn + j * 16 + r16;
        atomicAdd(&stats[col], s);
        atomicAdd(&stats[FD + col], qq);
      }
    }
  } else {
    float* outf = (float*)Cout + (size_t)half * M * FD;
    bf16_t* outb = (bf16_t*)Cout + (size_t)half * M * FD;
#pragma unroll
    for (int i = 0; i < 4; ++i) {
#pragma unroll
      for (int rg = 0; rg < 4; ++rg) {
        int gr = m0 + wm + i * 16 + q * 4 + rg;
        if (gr >= M) continue;
#pragma unroll
        for (int j = 0; j < 4; ++j) {
          int col = n0 + wn + j * 16 + r16;
          float y = acc[i][j][rg] + bcol[j];
          if (of32)
            outf[(size_t)gr * FD + col] = y;
          else
            outb[(size_t)gr * FD + col] = __float2bfloat16(y);
        }
      }
    }
  }
}

// ---------------- BN finalize + apply ----------------
__global__ void bn_fin_k(const float* __restrict__ stats, const void* gamma, const void* beta,
                         unsigned long long goff, float M, float* __restrict__ scsh,
                         const int* flag) {
  int f = *flag;
  for (int c = threadIdx.x; c < FD; c += 256) {
    float m = stats[c] / M;
    float v = fmaxf(stats[FD + c] / M - m * m, 0.f);
    float sc = ldf(gamma, goff + c, f) * rsqrtf(v + 1e-5f);
    scsh[c] = sc;
    scsh[FD + c] = ldf(beta, goff + c, f) - m * sc;
  }
}

__global__ void bn_apply_k(const bf16_t* __restrict__ x, const float* __restrict__ scsh,
                           bf16_t* __restrict__ out, int total8) {
  int p = blockIdx.x * 256 + threadIdx.x;
  if (p >= total8) return;
  int e = p * 8;
  int col = e & (FD - 1);
  uint4 u = *(const uint4*)(x + e);
  bf162_t* pr = (bf162_t*)&u;
  uint4 ov;
  bf162_t* po = (bf162_t*)&ov;
#pragma unroll
  for (int i = 0; i < 4; ++i) {
    float x0 = __bfloat162float(pr[i].x) * scsh[col + 2 * i] + scsh[FD + col + 2 * i];
    float x1 = __bfloat162float(pr[i].y) * scsh[col + 2 * i + 1] + scsh[FD + col + 2 * i + 1];
    po[i].x = __float2bfloat16(fmaxf(0.f, x0));
    po[i].y = __float2bfloat16(fmaxf(0.f, x1));
  }
  *(uint4*)(out + e) = ov;
}

// ---------------- host orchestration ----------------
extern "C" void kernel_launch(void* const* d_in, const int* in_sizes, int n_in,
                              void* d_out, int out_size, void* d_ws, size_t ws_size,
                              hipStream_t stream) {
  const int Mn = in_sizes[0] / FD;          // 20000
  const int Mp = (Mn + 127) & ~127;         // 20096
  const int E = in_sizes[14];               // 320000
  const size_t SZ = (size_t)FD * FD;

  const void* hd_raw = d_in[0];
  const void* hp_raw = d_in[1];
  const void* Ws1 = d_in[2];
  const void* Wn1 = d_in[3];
  const void* b1 = d_in[4];
  const void* Ws2 = d_in[5];
  const void* Wn2 = d_in[6];
  const void* b2 = d_in[7];
  const void* bng = d_in[8];
  const void* bnb = d_in[9];
  const void* pWd = d_in[10];
  const void* pbd = d_in[11];
  const void* pWp = d_in[12];
  const void* pbp = d_in[13];
  const int* a_src = (const int*)d_in[14];
  const int* a_dst = (const int*)d_in[15];
  const int* i_src = (const int*)d_in[16];
  const int* i_dst = (const int*)d_in[17];

  char* wptr = (char*)d_ws;
  auto alloc = [&](size_t bytes) {
    char* p = wptr;
    wptr += (bytes + 255) & ~(size_t)255;
    return p;
  };
  bf16_t* Bt = (bf16_t*)alloc(14 * SZ * 2);
  float* biasf = (float*)alloc(6 * FD * 4);
  float* stats = (float*)alloc(4 * FD * 4);  // [sum_d|sq_d|sum_p|sq_p]
  float* scshd = (float*)alloc(2 * FD * 4);
  float* scshp = (float*)alloc(2 * FD * 4);
  int* dtflag = (int*)alloc(256);
  int* deg = (int*)alloc((size_t)4 * Mn * 4);
  int* offs = (int*)alloc((size_t)4 * (Mn + 1) * 4);
  int* curs = (int*)alloc((size_t)4 * Mn * 4);
  int* evals = (int*)alloc((size_t)4 * E * 4);
  bf16_t* accb = (bf16_t*)alloc((size_t)Mp * FD * 2);  // bf16 pre-BN tensor (shared d/p)
  bf16_t* h_d = (bf16_t*)alloc((size_t)Mp * FD * 2);
  bf16_t* h_p = (bf16_t*)alloc((size_t)Mp * FD * 2);
  bf16_t* mean0 = (bf16_t*)alloc((size_t)Mp * FD * 2);
  bf16_t* mean1 = (bf16_t*)alloc((size_t)Mp * FD * 2);
  bf16_t* mean2 = (bf16_t*)alloc((size_t)Mp * FD * 2);
  bf16_t* mean3 = (bf16_t*)alloc((size_t)Mp * FD * 2);

  detect_k<<<1, 256, 0, stream>>>((const unsigned int*)hd_raw, 4096, dtflag);
  const int nh = Mn * FD, nhp = Mp * FD;
  conv_h_k<<<dim3((nhp / 4 + 255) / 256, 2), 256, 0, stream>>>(hd_raw, hp_raw, h_d, h_p, nh, nhp,
                                                               dtflag);

  hipMemsetAsync(deg, 0, (size_t)4 * Mn * 4, stream);
  int eb = (E + 255) / 256;
  count_deg_k<<<eb, 256, 0, stream>>>(a_src, a_dst, i_src, i_dst, deg, Mn, E);
  scan_k<<<4, 256, 0, stream>>>(deg, offs, curs, Mn);
  fill_k<<<dim3(eb, 4), 256, 0, stream>>>(a_src, a_dst, i_src, i_dst, curs, evals, Mn, E);

  // Bt slots: [0..3]=Wn1T[r], [4..7]=Wn2T[r], [8]=Ws1(0+2+3)T, [9]=Ws1(1)T,
  //           [10]=Ws2(0+2+3)T, [11]=Ws2(1)T, [12]=projWdT, [13]=projWpT
  TSlots ts;
  for (int z = 0; z < 14; ++z) { ts.s1[z] = -1; ts.s2[z] = -1; ts.o1[z] = 0; ts.o2[z] = 0; }
  for (int r = 0; r < 4; ++r) { ts.s0[r] = 1; ts.o0[r] = (unsigned long long)r * SZ; }
  for (int r = 0; r < 4; ++r) { ts.s0[4 + r] = 3; ts.o0[4 + r] = (unsigned long long)r * SZ; }
  ts.s0[8] = 0; ts.o0[8] = 0; ts.s1[8] = 0; ts.o1[8] = 2 * SZ; ts.s2[8] = 0; ts.o2[8] = 3 * SZ;
  ts.s0[9] = 0; ts.o0[9] = 1 * SZ;
  ts.s0[10] = 2; ts.o0[10] = 0; ts.s1[10] = 2; ts.o1[10] = 2 * SZ; ts.s2[10] = 2; ts.o2[10] = 3 * SZ;
  ts.s0[11] = 2; ts.o0[11] = 1 * SZ;
  ts.s0[12] = 4; ts.o0[12] = 0;
  ts.s0[13] = 5; ts.o0[13] = 0;
  transpose_all_k<<<dim3(16, 16, 14), dim3(32, 8), 0, stream>>>(Ws1, Wn1, Ws2, Wn2, pWd, pWp,
                                                                ts, Bt, dtflag);
  prep_bias_k<<<1, 256, 0, stream>>>(b1, b2, pbd, pbp, biasf, dtflag);

  dim3 ggrid(4, Mp / 128);
  const int bn8 = (Mn * FD / 8 + 255) / 256;

  auto layer = [&](int wn0, int wsp, int wsd, const float* bd, const float* bp,
                   unsigned long long goff_d, unsigned long long goff_p) {
    seg_mean4_k<<<dim3(Mp, 4), 256, 0, stream>>>(h_d, h_p, offs, evals, Mn, E, mean0, mean1,
                                                 mean2, mean3);
    hipMemsetAsync(stats, 0, 4 * FD * 4, stream);
    // disease = hd@Ws[1] + mean1@Wn[1] + b   (K-concat, 2 segments)
    gemm_f<2, 0><<<ggrid, 256, 0, stream>>>(h_d, mean1, nullptr, nullptr,
                                            Bt + (size_t)wsd * SZ, Bt + (size_t)(wn0 + 1) * SZ,
                                            nullptr, nullptr, bd, accb, stats, Mn, dtflag);
    bn_fin_k<<<1, 256, 0, stream>>>(stats, bng, bnb, goff_d, (float)Mn, scshd, dtflag);
    bn_apply_k<<<bn8, 256, 0, stream>>>(accb, scshd, h_d, Mn * FD / 8);
    // protein = hp@(Ws0+Ws2+Ws3) + mean0@Wn0 + mean2@Wn2 + mean3@Wn3 + b   (4 segments)
    gemm_f<4, 0><<<ggrid, 256, 0, stream>>>(h_p, mean0, mean2, mean3,
                                            Bt + (size_t)wsp * SZ, Bt + (size_t)(wn0 + 0) * SZ,
                                            Bt + (size_t)(wn0 + 2) * SZ,
                                            Bt + (size_t)(wn0 + 3) * SZ, bp, accb,
                                            stats + 2 * FD, Mn, dtflag);
    bn_fin_k<<<1, 256, 0, stream>>>(stats + 2 * FD, bng, bnb, goff_p, (float)Mn, scshp, dtflag);
    bn_apply_k<<<bn8, 256, 0, stream>>>(accb, scshp, h_p, Mn * FD / 8);
  };

  // bn params layout [layer][ntype][512], ntype 0=disease 1=protein
  layer(0, 8, 9, biasf + 0 * FD, biasf + 1 * FD, 0ULL * FD, 1ULL * FD);
  layer(4, 10, 11, biasf + 2 * FD, biasf + 3 * FD, 2ULL * FD, 3ULL * FD);

  // merged final projections -> d_out (z=0: disease half, z=1: protein half)
  gemm_f<1, 1><<<dim3(4, Mp / 128, 2), 256, 0, stream>>>(
      h_d, h_p, nullptr, nullptr, Bt + 12 * SZ, Bt + 13 * SZ, nullptr, nullptr,
      biasf + 4 * FD, d_out, nullptr, Mn, dtflag);
}